// Round 3
// baseline (1041.272 us; speedup 1.0000x reference)
//
#include <hip/hip_runtime.h>
#include <hip/hip_fp16.h>
#include <math.h>

#define NN 100000
#define NE 6400000
#define INCH 128
#define BSH 7                       // bucket = 128 dst nodes
#define BW (1 << BSH)
#define NBKT ((NN + BW - 1) / BW)   // 782
#define BCAP 9216                   // slots/bucket (mean 8192, +11 sigma)
#define BNP 800                     // bn_part column stride (>= NBKT)

// fp16 pack/unpack helpers (h rows stored as 10xfp16 + fp32 logits, 32 B)
__device__ inline float pkh(float a, float b) {
  __half2 h = __floats2half2_rn(a, b);
  return __uint_as_float(*reinterpret_cast<unsigned int*>(&h));
}
__device__ inline float2 uph(float f) {
  unsigned int b = __float_as_uint(f);
  __half2 h = *reinterpret_cast<__half2*>(&b);
  return __half22float2(h);
}

// ---- Phase 1a: zero the per-node degree counters ---------------------------
__global__ __launch_bounds__(256) void k_zero(int* __restrict__ nodecnt) {
  int i = blockIdx.x * blockDim.x + threadIdx.x;
  if (i < NN) nodecnt[i] = 0;
}

// ---- Phase 1b: per-node degree histogram (global atomics, ~100K bins) ------
__global__ __launch_bounds__(256) void k_hist(const int* __restrict__ ei,
                                              int* __restrict__ nodecnt) {
  int i = blockIdx.x * blockDim.x + threadIdx.x;
  if (i < NE) atomicAdd(&nodecnt[ei[NE + i]], 1);
}

// ---- Phase 2: per-bucket scan of node counts -> oc, cursor, bcnt -----------
// oc[n] = (start_within_bucket << 16) | count; cursor[n] = absolute write pos.
__global__ __launch_bounds__(128) void k_nodescan(
    const int* __restrict__ nodecnt, unsigned int* __restrict__ oc,
    int* __restrict__ cursor, int* __restrict__ bcnt) {
  __shared__ int wsum[2];
  int b = blockIdx.x, t = threadIdx.x;
  int lane = t & 63, w = t >> 6;
  int n = (b << BSH) + t;
  int c = (n < NN) ? nodecnt[n] : 0;
  int v = c;
#pragma unroll
  for (int off = 1; off < 64; off <<= 1) {
    int u = __shfl_up(v, off, 64);
    if (lane >= off) v += u;
  }
  if (lane == 63) wsum[w] = v;
  __syncthreads();
  int base = (w == 1) ? wsum[0] : 0;
  int start = base + v - c;  // exclusive prefix within bucket
  if (n < NN) {
    oc[n] = ((unsigned int)start << 16) | (unsigned int)c;
    cursor[n] = b * BCAP + start;
  }
  if (t == 127) bcnt[b] = wsum[0] + v;
}

// ---- Phase 3: direct scatter to final sorted position (per-node cursors) ---
__global__ __launch_bounds__(256) void k_sdir(const int* __restrict__ ei,
                                              int* __restrict__ cursor,
                                              unsigned int* __restrict__ pairs) {
  int i = blockIdx.x * blockDim.x + threadIdx.x;
  if (i >= NE) return;
  int s = ei[i], d = ei[NE + i];
  int pos = atomicAdd(&cursor[d], 1);
  int b = d >> BSH;
  unsigned int rel = (unsigned int)(pos - b * BCAP);
  if (rel < BCAP) pairs[(size_t)b * BCAP + rel] = (unsigned int)s;
}

// ---------------- Layer 1 node: h1 = x@W1 -> fp16 row; logits fp32 ----------
// h1 row (8 dwords = 32 B): [h01,h23,h45,h67,h89 packed fp16, pad, asx, asy]
__global__ __launch_bounds__(256) void k_l1_node(
    const float* __restrict__ x, const float* __restrict__ W1,
    const float* __restrict__ a_src1, const float* __restrict__ a_dst1,
    float* __restrict__ h1, float2* __restrict__ ad1) {
  __shared__ float Wt[10 * INCH];
  __shared__ float asw[10], adw[10];
  for (int i = threadIdx.x; i < 10 * INCH; i += blockDim.x) {
    int c = i / 10, k = i - c * 10;
    Wt[k * INCH + c] = W1[i];
  }
  if (threadIdx.x < 10) {
    asw[threadIdx.x] = a_src1[threadIdx.x];
    adw[threadIdx.x] = a_dst1[threadIdx.x];
  }
  __syncthreads();
  int n = blockIdx.x * blockDim.x + threadIdx.x;
  if (n >= NN) return;
  const float4* xr = (const float4*)(x + (size_t)n * INCH);
  const float4* Wt4 = (const float4*)Wt;
  float acc[10];
#pragma unroll
  for (int k = 0; k < 10; k++) acc[k] = 0.f;
#pragma unroll 8
  for (int c4 = 0; c4 < INCH / 4; c4++) {
    float4 xv = xr[c4];
#pragma unroll
    for (int k = 0; k < 10; k++) {
      float4 wv = Wt4[k * (INCH / 4) + c4];
      acc[k] += xv.x * wv.x + xv.y * wv.y + xv.z * wv.z + xv.w * wv.w;
    }
  }
  float s0 = 0.f, s1 = 0.f, d0 = 0.f, d1 = 0.f;
#pragma unroll
  for (int j = 0; j < 5; j++) {
    s0 += acc[j] * asw[j];
    s1 += acc[5 + j] * asw[5 + j];
    d0 += acc[j] * adw[j];
    d1 += acc[5 + j] * adw[5 + j];
  }
  float4* hrow = (float4*)(h1 + (size_t)n * 8);
  hrow[0] = make_float4(pkh(acc[0], acc[1]), pkh(acc[2], acc[3]),
                        pkh(acc[4], acc[5]), pkh(acc[6], acc[7]));
  hrow[1] = make_float4(pkh(acc[8], acc[9]), 0.f, s0, s1);
  ad1[n] = make_float2(d0, d1);
}

// ---- L1 agg: LDS-stage pre-sorted bucket (coalesced), then gather ----------
__global__ __launch_bounds__(512, 8) void k_l1_aggs(
    const int* __restrict__ bcnt,
    const unsigned int* __restrict__ sorted_g, const unsigned int* __restrict__ oc,
    const float* __restrict__ h1, const float2* __restrict__ ad1,
    const float* __restrict__ b1, float* __restrict__ g1,
    float* __restrict__ bn_part) {
  __shared__ __align__(16) unsigned int sorted[BCAP];
  __shared__ float biasS[10];
  __shared__ float bn_lds[8 * 20];
  int t = threadIdx.x;
  int w = t >> 6;
  int b = blockIdx.x;
  int base_n = b << BSH;
  if (t < 10) biasS[t] = b1[t];
  // coalesced copy of the occupied part of the bucket: 16 B per lane per iter
  {
    int cb = bcnt[b];
    cb = cb > BCAP ? BCAP : cb;
    int n4 = (cb + 3) >> 2;
    const uint4* pp4 = (const uint4*)(sorted_g + (size_t)b * BCAP);
    uint4* s4 = (uint4*)sorted;
    for (int k = t; k < n4; k += 512) s4[k] = pp4[k];
  }
  __syncthreads();
  // gather: node = t>>2 (adjacent lanes), part = t&3; shfl_xor combine
  int node = t >> 2;
  int part = t & 3;
  int n = base_n + node;
  bool valid = n < NN;
  unsigned int ocv = valid ? oc[n] : 0u;
  int s0i = (int)(ocv >> 16);
  int c = (int)(ocv & 0xffffu);
  float2 adn = valid ? ad1[n] : make_float2(0.f, 0.f);
  float acc[10];
#pragma unroll
  for (int j = 0; j < 10; j++) acc[j] = 0.f;
  float den0 = 0.f, den1 = 0.f;
  for (int k = part; k < c; k += 4) {
    int s = (int)sorted[s0i + k];
    const float4* hs = (const float4*)(h1 + (size_t)s * 8);
    float4 ra = hs[0], rb = hs[1];
    float e0 = rb.z + adn.x; e0 = e0 > 0.f ? e0 : 0.2f * e0;
    float e1 = rb.w + adn.y; e1 = e1 > 0.f ? e1 : 0.2f * e1;
    float x0 = expf(e0), x1 = expf(e1);
    float2 h01 = uph(ra.x), h23 = uph(ra.y), h45 = uph(ra.z), h67 = uph(ra.w),
           h89 = uph(rb.x);
    acc[0] += x0 * h01.x;  acc[1] += x0 * h01.y;  acc[2] += x0 * h23.x;
    acc[3] += x0 * h23.y;  acc[4] += x0 * h45.x;
    acc[5] += x1 * h45.y;  acc[6] += x1 * h67.x;  acc[7] += x1 * h67.y;
    acc[8] += x1 * h89.x;  acc[9] += x1 * h89.y;
    den0 += x0; den1 += x1;
  }
#pragma unroll
  for (int j = 0; j < 10; j++) {
    acc[j] += __shfl_xor(acc[j], 1, 64);
    acc[j] += __shfl_xor(acc[j], 2, 64);
  }
  den0 += __shfl_xor(den0, 1, 64); den0 += __shfl_xor(den0, 2, 64);
  den1 += __shfl_xor(den1, 1, 64); den1 += __shfl_xor(den1, 2, 64);
  float v[10];
#pragma unroll
  for (int j = 0; j < 10; j++) v[j] = 0.f;
  if (part == 0 && valid) {
    // self-loop (src == dst == n)
    const float4* hs = (const float4*)(h1 + (size_t)n * 8);
    float4 ra = hs[0], rb = hs[1];
    float e0 = rb.z + adn.x; e0 = e0 > 0.f ? e0 : 0.2f * e0;
    float e1 = rb.w + adn.y; e1 = e1 > 0.f ? e1 : 0.2f * e1;
    float x0 = expf(e0), x1 = expf(e1);
    float2 h01 = uph(ra.x), h23 = uph(ra.y), h45 = uph(ra.z), h67 = uph(ra.w),
           h89 = uph(rb.x);
    acc[0] += x0 * h01.x;  acc[1] += x0 * h01.y;  acc[2] += x0 * h23.x;
    acc[3] += x0 * h23.y;  acc[4] += x0 * h45.x;
    acc[5] += x1 * h45.y;  acc[6] += x1 * h67.x;  acc[7] += x1 * h67.y;
    acc[8] += x1 * h89.x;  acc[9] += x1 * h89.y;
    den0 += x0; den1 += x1;
    float i0 = 1.f / (den0 + 1e-16f), i1 = 1.f / (den1 + 1e-16f);
#pragma unroll
    for (int j = 0; j < 5; j++) v[j] = acc[j] * i0 + biasS[j];
#pragma unroll
    for (int j = 5; j < 10; j++) v[j] = acc[j] * i1 + biasS[j];
    float4* gr = (float4*)(g1 + (size_t)n * 12);
    gr[0] = make_float4(v[0], v[1], v[2], v[3]);
    gr[1] = make_float4(v[4], v[5], v[6], v[7]);
    gr[2] = make_float4(v[8], v[9], 0.f, 0.f);
  }
  // BN partials: nonzero only at part==0 lanes (spacing 4) -> 4-stage reduce
  float s[20];
#pragma unroll
  for (int j = 0; j < 10; j++) { s[j] = v[j]; s[10 + j] = v[j] * v[j]; }
#pragma unroll
  for (int j = 0; j < 20; j++) {
    s[j] += __shfl_down(s[j], 4, 64);
    s[j] += __shfl_down(s[j], 8, 64);
    s[j] += __shfl_down(s[j], 16, 64);
    s[j] += __shfl_down(s[j], 32, 64);
  }
  if ((t & 63) == 0) {
#pragma unroll
    for (int j = 0; j < 20; j++) bn_lds[w * 20 + j] = s[j];
  }
  __syncthreads();
  if (t == 0) {
#pragma unroll
    for (int j = 0; j < 20; j++) {
      float acc20 = 0.f;
#pragma unroll
      for (int ww = 0; ww < 8; ww++) acc20 += bn_lds[ww * 20 + j];
      bn_part[j * BNP + b] = acc20;  // unique slot, no atomic
    }
  }
}

// ---- BN final reduce: one block per channel-stat, no contended atomics -----
__global__ __launch_bounds__(64) void k_bnred(const float* __restrict__ bn_part,
                                              float* __restrict__ bns) {
  int j = blockIdx.x;  // 0..19
  int lane = threadIdx.x;
  float s = 0.f;
  for (int b = lane; b < NBKT; b += 64) s += bn_part[j * BNP + b];
#pragma unroll
  for (int off = 32; off > 0; off >>= 1) s += __shfl_down(s, off, 64);
  if (lane == 0) bns[j] = s;
}

// -------- Layer 2 node: BN + ELU + h2 = hn@W2 -> fp16 row; as2 fp32 ---------
// h2 row (8 dwords): [o01,o23,o45,o67,o89 packed fp16, pad, ss, pad]
__global__ __launch_bounds__(256) void k_l2_node(
    const float* __restrict__ g1, const float* __restrict__ bns,
    const float* __restrict__ gamma1, const float* __restrict__ beta1,
    const float* __restrict__ W2, const float* __restrict__ a_src2,
    const float* __restrict__ a_dst2, float* __restrict__ h2,
    float* __restrict__ ad2) {
  __shared__ float scale[10], shift[10], W2s[100], a2s[10], a2d[10];
  if (threadIdx.x < 10) {
    int j = threadIdx.x;
    float mu = bns[j] * (1.f / NN);
    float var = bns[10 + j] * (1.f / NN) - mu * mu;
    float rs = rsqrtf(var + 1e-5f);
    scale[j] = rs * gamma1[j];
    shift[j] = beta1[j] - mu * rs * gamma1[j];
    a2s[j] = a_src2[j];
    a2d[j] = a_dst2[j];
  }
  for (int i = threadIdx.x; i < 100; i += blockDim.x) W2s[i] = W2[i];
  __syncthreads();
  int n = blockIdx.x * blockDim.x + threadIdx.x;
  if (n >= NN) return;
  const float4* gr = (const float4*)(g1 + (size_t)n * 12);
  float4 g0 = gr[0], g1v = gr[1], g2 = gr[2];
  float hv[10] = {g0.x, g0.y, g0.z, g0.w, g1v.x, g1v.y, g1v.z, g1v.w, g2.x, g2.y};
#pragma unroll
  for (int j = 0; j < 10; j++) {
    float t = hv[j] * scale[j] + shift[j];
    hv[j] = t > 0.f ? t : expm1f(t);  // ELU
  }
  float o[10];
#pragma unroll
  for (int k = 0; k < 10; k++) o[k] = 0.f;
#pragma unroll
  for (int c = 0; c < 10; c++) {
#pragma unroll
    for (int k = 0; k < 10; k++) o[k] += hv[c] * W2s[c * 10 + k];
  }
  float ss = 0.f, sd = 0.f;
#pragma unroll
  for (int k = 0; k < 10; k++) { ss += o[k] * a2s[k]; sd += o[k] * a2d[k]; }
  float4* hr = (float4*)(h2 + (size_t)n * 8);
  hr[0] = make_float4(pkh(o[0], o[1]), pkh(o[2], o[3]), pkh(o[4], o[5]),
                      pkh(o[6], o[7]));
  hr[1] = make_float4(pkh(o[8], o[9]), 0.f, ss, 0.f);
  ad2[n] = sd;
}

// ---- L2 agg: LDS-stage pre-sorted bucket, 1 head, writes final out ---------
__global__ __launch_bounds__(512, 8) void k_l2_aggs(
    const int* __restrict__ bcnt,
    const unsigned int* __restrict__ sorted_g, const unsigned int* __restrict__ oc,
    const float* __restrict__ h2, const float* __restrict__ ad2,
    const float* __restrict__ b2, float* __restrict__ out) {
  __shared__ __align__(16) unsigned int sorted[BCAP];
  __shared__ float biasS[10];
  int t = threadIdx.x;
  int b = blockIdx.x;
  int base_n = b << BSH;
  if (t < 10) biasS[t] = b2[t];
  {
    int cb = bcnt[b];
    cb = cb > BCAP ? BCAP : cb;
    int n4 = (cb + 3) >> 2;
    const uint4* pp4 = (const uint4*)(sorted_g + (size_t)b * BCAP);
    uint4* s4 = (uint4*)sorted;
    for (int k = t; k < n4; k += 512) s4[k] = pp4[k];
  }
  __syncthreads();
  int node = t >> 2;
  int part = t & 3;
  int n = base_n + node;
  bool valid = n < NN;
  unsigned int ocv = valid ? oc[n] : 0u;
  int s0i = (int)(ocv >> 16);
  int c = (int)(ocv & 0xffffu);
  float adn = valid ? ad2[n] : 0.f;
  float acc[10];
#pragma unroll
  for (int j = 0; j < 10; j++) acc[j] = 0.f;
  float den = 0.f;
  for (int k = part; k < c; k += 4) {
    int s = (int)sorted[s0i + k];
    const float4* hs = (const float4*)(h2 + (size_t)s * 8);
    float4 ra = hs[0], rb = hs[1];
    float ee = rb.z + adn; ee = ee > 0.f ? ee : 0.2f * ee;
    float xv = expf(ee);
    float2 h01 = uph(ra.x), h23 = uph(ra.y), h45 = uph(ra.z), h67 = uph(ra.w),
           h89 = uph(rb.x);
    acc[0] += xv * h01.x;  acc[1] += xv * h01.y;  acc[2] += xv * h23.x;
    acc[3] += xv * h23.y;  acc[4] += xv * h45.x;  acc[5] += xv * h45.y;
    acc[6] += xv * h67.x;  acc[7] += xv * h67.y;  acc[8] += xv * h89.x;
    acc[9] += xv * h89.y;
    den += xv;
  }
#pragma unroll
  for (int j = 0; j < 10; j++) {
    acc[j] += __shfl_xor(acc[j], 1, 64);
    acc[j] += __shfl_xor(acc[j], 2, 64);
  }
  den += __shfl_xor(den, 1, 64); den += __shfl_xor(den, 2, 64);
  if (part == 0 && valid) {
    const float4* hs = (const float4*)(h2 + (size_t)n * 8);  // self-loop
    float4 ra = hs[0], rb = hs[1];
    float ee = rb.z + adn; ee = ee > 0.f ? ee : 0.2f * ee;
    float xv = expf(ee);
    float2 h01 = uph(ra.x), h23 = uph(ra.y), h45 = uph(ra.z), h67 = uph(ra.w),
           h89 = uph(rb.x);
    acc[0] += xv * h01.x;  acc[1] += xv * h01.y;  acc[2] += xv * h23.x;
    acc[3] += xv * h23.y;  acc[4] += xv * h45.x;  acc[5] += xv * h45.y;
    acc[6] += xv * h67.x;  acc[7] += xv * h67.y;  acc[8] += xv * h89.x;
    acc[9] += xv * h89.y;
    den += xv;
    float inv = 1.f / (den + 1e-16f);
    float2* orow = (float2*)(out + (size_t)n * 10);
    orow[0] = make_float2(acc[0] * inv + biasS[0], acc[1] * inv + biasS[1]);
    orow[1] = make_float2(acc[2] * inv + biasS[2], acc[3] * inv + biasS[3]);
    orow[2] = make_float2(acc[4] * inv + biasS[4], acc[5] * inv + biasS[5]);
    orow[3] = make_float2(acc[6] * inv + biasS[6], acc[7] * inv + biasS[7]);
    orow[4] = make_float2(acc[8] * inv + biasS[8], acc[9] * inv + biasS[9]);
  }
}

extern "C" void kernel_launch(void* const* d_in, const int* in_sizes, int n_in,
                              void* d_out, int out_size, void* d_ws, size_t ws_size,
                              hipStream_t stream) {
  const float* x      = (const float*)d_in[0];
  const float* W1     = (const float*)d_in[1];
  const float* a_src1 = (const float*)d_in[2];
  const float* a_dst1 = (const float*)d_in[3];
  const float* b1     = (const float*)d_in[4];
  const float* gamma1 = (const float*)d_in[5];
  const float* beta1  = (const float*)d_in[6];
  const float* W2     = (const float*)d_in[7];
  const float* a_src2 = (const float*)d_in[8];
  const float* a_dst2 = (const float*)d_in[9];
  const float* b2     = (const float*)d_in[10];
  const int*   ei     = (const int*)d_in[11];
  float* out = (float*)d_out;

  // Workspace layout (4B units). All regions fully written before read.
  int* bcnt = (int*)d_ws;                               // NBKT (k_nodescan)
  unsigned int* pairs = (unsigned int*)d_ws + 1024;     // NBKT*BCAP
  float* h1 = (float*)(pairs + (size_t)NBKT * BCAP);    // NN*8 (fp16 rows)
  float* ad1 = h1 + (size_t)NN * 8;                     // NN*2
  float* g1 = ad1 + (size_t)NN * 2;                     // NN*12
  float* h2 = g1 + (size_t)NN * 12;                     // NN*8 (fp16 rows)
  float* ad2 = h2 + (size_t)NN * 8;                     // NN
  float* bn_part = ad2 + NN;                            // 20*BNP
  float* bns = bn_part + 20 * BNP;                      // 20
  int* nodecnt = (int*)(bns + 20 + 12);                 // NN
  int* cursor = nodecnt + NN;                           // NN
  unsigned int* oc = (unsigned int*)(cursor + NN);      // NN

  const int B = 256;
  const int gN = (NN + B - 1) / B;               // 391
  const int gE = (NE + B - 1) / B;               // 25000

  k_zero<<<gN, B, 0, stream>>>(nodecnt);
  k_hist<<<gE, B, 0, stream>>>(ei, nodecnt);
  k_nodescan<<<NBKT, 128, 0, stream>>>(nodecnt, oc, cursor, bcnt);
  k_sdir<<<gE, B, 0, stream>>>(ei, cursor, pairs);
  k_l1_node<<<gN, B, 0, stream>>>(x, W1, a_src1, a_dst1, h1, (float2*)ad1);
  k_l1_aggs<<<NBKT, 512, 0, stream>>>(bcnt, pairs, oc, h1, (const float2*)ad1,
                                      b1, g1, bn_part);
  k_bnred<<<20, 64, 0, stream>>>(bn_part, bns);
  k_l2_node<<<gN, B, 0, stream>>>(g1, bns, gamma1, beta1, W2, a_src2, a_dst2,
                                  h2, ad2);
  k_l2_aggs<<<NBKT, 512, 0, stream>>>(bcnt, pairs, oc, h2, ad2, b2, out);
}

// Round 4
// 318.525 us; speedup vs baseline: 3.2690x; 3.2690x over previous
//
#include <hip/hip_runtime.h>
#include <hip/hip_fp16.h>
#include <math.h>

#define NN 100000
#define NE 6400000
#define INCH 128
#define BSH 7                       // bucket = 128 dst nodes
#define BW (1 << BSH)
#define NBKT ((NN + BW - 1) / BW)   // 782
#define NBP 784                     // padded row stride for cntmat/basemat
#define BCAP 9216                   // slots/bucket (mean 8192, +11 sigma)
#define BIN_CH 8192                 // edges per bin block
#define BNP 800                     // bn_part column stride (>= NBKT)

// fp16 pack/unpack helpers (h rows stored as 10xfp16 + fp32 logits, 32 B)
__device__ inline float pkh(float a, float b) {
  __half2 h = __floats2half2_rn(a, b);
  return __uint_as_float(*reinterpret_cast<unsigned int*>(&h));
}
__device__ inline float2 uph(float f) {
  unsigned int b = __float_as_uint(f);
  __half2 h = *reinterpret_cast<__half2*>(&b);
  return __half22float2(h);
}

// ---- Phase 1: per-chunk bucket histogram -> dense cntmat (no atomics) ------
__global__ __launch_bounds__(512) void k_count(const int* __restrict__ ei,
                                               int* __restrict__ cntmat) {
  __shared__ int cnt4[4][NBKT];
  int t = threadIdx.x;
  int w = (t >> 6) & 3;
  for (int i = t; i < 4 * NBKT; i += 512) (&cnt4[0][0])[i] = 0;
  __syncthreads();
  int c0 = blockIdx.x * BIN_CH;
  int c1 = c0 + BIN_CH < NE ? c0 + BIN_CH : NE;
  int n4 = (c1 - c0) >> 2;  // NE and BIN_CH divisible by 4
  const int4* d4 = (const int4*)(ei + NE + c0);
  for (int k = t; k < n4; k += 512) {
    int4 v = d4[k];
    atomicAdd(&cnt4[w][v.x >> BSH], 1);
    atomicAdd(&cnt4[w][v.y >> BSH], 1);
    atomicAdd(&cnt4[w][v.z >> BSH], 1);
    atomicAdd(&cnt4[w][v.w >> BSH], 1);
  }
  __syncthreads();
  for (int b = t; b < NBKT; b += 512)
    cntmat[(size_t)b * NBP + blockIdx.x] =
        cnt4[0][b] + cnt4[1][b] + cnt4[2][b] + cnt4[3][b];
}

// ---- Phase 2: per-bucket prefix over chunks (wave scan, no atomics) --------
__global__ __launch_bounds__(64) void k_scanb(const int* __restrict__ cntmat,
                                              int* __restrict__ basemat,
                                              int* __restrict__ bcnt) {
  int j = blockIdx.x;  // bucket
  int lane = threadIdx.x;
  int carry = 0;
  for (int i0 = 0; i0 < NBKT; i0 += 64) {
    int i = i0 + lane;
    int v0 = (i < NBKT) ? cntmat[(size_t)j * NBP + i] : 0;
    int v = v0;
#pragma unroll
    for (int off = 1; off < 64; off <<= 1) {
      int u = __shfl_up(v, off, 64);
      if (lane >= off) v += u;
    }
    if (i < NBKT) basemat[(size_t)i * NBP + j] = carry + v - v0;  // exclusive
    carry += __shfl(v, 63, 64);  // chunk total, uniform
  }
  if (lane == 0) bcnt[j] = carry;
}

// ---- Phase 3: LDS-staged counting sort; 1024 threads for latency hiding ----
// Entry packing: (src << 7) | (dst & 127)  -- 24 bits used.
__global__ __launch_bounds__(1024) void k_scatter2(
    const int* __restrict__ ei, const int* __restrict__ cntmat,
    const int* __restrict__ basemat, unsigned int* __restrict__ pairs) {
  __shared__ int offs[NBKT];           // staging exclusive offsets
  __shared__ int cur[NBKT];            // shared cursors (low contention)
  __shared__ int gbase[NBKT];          // global base per bucket (precomputed)
  __shared__ int scanp[1024];
  __shared__ unsigned int stage[BIN_CH];
  __shared__ unsigned short sbkt[BIN_CH];  // bucket id per staged entry
  int t = threadIdx.x;
  int chunk = blockIdx.x;
  int myb0 = t * 4;
  int tots[4];
  int asum = 0;
#pragma unroll
  for (int j = 0; j < 4; j++) {
    int b = myb0 + j;
    int tt = (b < NBKT) ? cntmat[(size_t)b * NBP + chunk] : 0;
    tots[j] = tt;
    asum += tt;
  }
  for (int b = t; b < NBKT; b += 1024)
    gbase[b] = basemat[(size_t)chunk * NBP + b];
  scanp[t] = asum;
  __syncthreads();
  for (int off = 1; off < 1024; off <<= 1) {
    int v = (t >= off) ? scanp[t - off] : 0;
    __syncthreads();
    scanp[t] += v;
    __syncthreads();
  }
  int run = (t == 0) ? 0 : scanp[t - 1];
#pragma unroll
  for (int j = 0; j < 4; j++) {
    int b = myb0 + j;
    if (b < NBKT) {
      offs[b] = run;
      cur[b] = run;
      run += tots[j];
    }
  }
  __syncthreads();
  int c0 = chunk * BIN_CH;
  int c1 = c0 + BIN_CH < NE ? c0 + BIN_CH : NE;
  for (int i = c0 + t; i < c1; i += 1024) {
    int s = ei[i], d = ei[NE + i];
    int bkt = d >> BSH;
    int pos = atomicAdd(&cur[bkt], 1);
    stage[pos] = ((unsigned int)s << BSH) | (unsigned int)(d & (BW - 1));
    sbkt[pos] = (unsigned short)bkt;
  }
  __syncthreads();
  int total = c1 - c0;
  for (int i = t; i < total; i += 1024) {
    unsigned int e = stage[i];
    int b = sbkt[i];
    int gp = gbase[b] + (i - offs[b]);
    if (gp < BCAP) pairs[(size_t)b * BCAP + gp] = e;
  }
}

// ---- Phase 4: per-bucket counting sort ONCE, in place; 1024 threads --------
// After this kernel, pairs[b*BCAP + i] holds src ids sorted by dst-local, and
// oc[n] = (start_within_bucket << 16) | count. Both agg kernels reuse it.
__global__ __launch_bounds__(1024) void k_sortb(
    const int* __restrict__ bcnt, unsigned int* __restrict__ pairs,
    unsigned int* __restrict__ oc) {
  __shared__ int cnt16[16][BW];      // per-wave counts / cursors
  __shared__ int wb16[16][BW];       // per-wave scatter base
  __shared__ int tot[BW];
  __shared__ int scanbuf[BW];
  __shared__ unsigned int sorted[BCAP];
  int t = threadIdx.x;
  int w = t >> 6;
  int b = blockIdx.x;
  int base_n = b << BSH;
  for (int i = t; i < 16 * BW; i += 1024) (&cnt16[0][0])[i] = 0;
  __syncthreads();
  int cntb = bcnt[b];
  cntb = cntb > BCAP ? BCAP : cntb;
  unsigned int* pp = pairs + (size_t)b * BCAP;
  for (int k = t; k < cntb; k += 1024)
    atomicAdd(&cnt16[w][pp[k] & (BW - 1)], 1);
  __syncthreads();
  if (t < BW) {
    int tt = 0;
#pragma unroll
    for (int j = 0; j < 16; j++) tt += cnt16[j][t];
    tot[t] = tt;
    scanbuf[t] = tt;
  }
  __syncthreads();
  for (int step = 1; step < BW; step <<= 1) {  // Hillis-Steele inclusive scan
    int v = 0;
    if (t < BW && t >= step) v = scanbuf[t - step];
    __syncthreads();
    if (t < BW) scanbuf[t] += v;
    __syncthreads();
  }
  if (t < BW) {
    int run = scanbuf[t] - tot[t];  // exclusive start for this dst-local
    int n = base_n + t;
    if (n < NN) oc[n] = ((unsigned int)run << 16) | (unsigned int)tot[t];
#pragma unroll
    for (int j = 0; j < 16; j++) { wb16[j][t] = run; run += cnt16[j][t]; cnt16[j][t] = 0; }
  }
  __syncthreads();
  for (int k = t; k < cntb; k += 1024) {
    unsigned int e = pp[k];
    int dl = e & (BW - 1);
    int pos = wb16[w][dl] + atomicAdd(&cnt16[w][dl], 1);
    sorted[pos] = e >> BSH;  // store src id only
  }
  __syncthreads();
  for (int k = t; k < cntb; k += 1024) pp[k] = sorted[k];  // in-place writeback
}

// ---------------- Layer 1 node: h1 = x@W1 -> fp16 row; logits fp32 ----------
// h1 row (8 dwords = 32 B): [h01,h23,h45,h67,h89 packed fp16, pad, asx, asy]
__global__ __launch_bounds__(256) void k_l1_node(
    const float* __restrict__ x, const float* __restrict__ W1,
    const float* __restrict__ a_src1, const float* __restrict__ a_dst1,
    float* __restrict__ h1, float2* __restrict__ ad1) {
  __shared__ float Wt[10 * INCH];
  __shared__ float asw[10], adw[10];
  for (int i = threadIdx.x; i < 10 * INCH; i += blockDim.x) {
    int c = i / 10, k = i - c * 10;
    Wt[k * INCH + c] = W1[i];
  }
  if (threadIdx.x < 10) {
    asw[threadIdx.x] = a_src1[threadIdx.x];
    adw[threadIdx.x] = a_dst1[threadIdx.x];
  }
  __syncthreads();
  int n = blockIdx.x * blockDim.x + threadIdx.x;
  if (n >= NN) return;
  const float4* xr = (const float4*)(x + (size_t)n * INCH);
  const float4* Wt4 = (const float4*)Wt;
  float acc[10];
#pragma unroll
  for (int k = 0; k < 10; k++) acc[k] = 0.f;
#pragma unroll 8
  for (int c4 = 0; c4 < INCH / 4; c4++) {
    float4 xv = xr[c4];
#pragma unroll
    for (int k = 0; k < 10; k++) {
      float4 wv = Wt4[k * (INCH / 4) + c4];
      acc[k] += xv.x * wv.x + xv.y * wv.y + xv.z * wv.z + xv.w * wv.w;
    }
  }
  float s0 = 0.f, s1 = 0.f, d0 = 0.f, d1 = 0.f;
#pragma unroll
  for (int j = 0; j < 5; j++) {
    s0 += acc[j] * asw[j];
    s1 += acc[5 + j] * asw[5 + j];
    d0 += acc[j] * adw[j];
    d1 += acc[5 + j] * adw[5 + j];
  }
  float4* hrow = (float4*)(h1 + (size_t)n * 8);
  hrow[0] = make_float4(pkh(acc[0], acc[1]), pkh(acc[2], acc[3]),
                        pkh(acc[4], acc[5]), pkh(acc[6], acc[7]));
  hrow[1] = make_float4(pkh(acc[8], acc[9]), 0.f, s0, s1);
  ad1[n] = make_float2(d0, d1);
}

// ---- L1 agg: LDS-stage pre-sorted bucket (coalesced), then gather ----------
__global__ __launch_bounds__(512, 8) void k_l1_aggs(
    const int* __restrict__ bcnt,
    const unsigned int* __restrict__ sorted_g, const unsigned int* __restrict__ oc,
    const float* __restrict__ h1, const float2* __restrict__ ad1,
    const float* __restrict__ b1, float* __restrict__ g1,
    float* __restrict__ bn_part) {
  __shared__ __align__(16) unsigned int sorted[BCAP];
  __shared__ float biasS[10];
  __shared__ float bn_lds[8 * 20];
  int t = threadIdx.x;
  int w = t >> 6;
  int b = blockIdx.x;
  int base_n = b << BSH;
  if (t < 10) biasS[t] = b1[t];
  // coalesced copy of the occupied part of the bucket: 16 B per lane per iter
  {
    int cb = bcnt[b];
    cb = cb > BCAP ? BCAP : cb;
    int n4 = (cb + 3) >> 2;
    const uint4* pp4 = (const uint4*)(sorted_g + (size_t)b * BCAP);
    uint4* s4 = (uint4*)sorted;
    for (int k = t; k < n4; k += 512) s4[k] = pp4[k];
  }
  __syncthreads();
  // gather: node = t>>2 (adjacent lanes), part = t&3; shfl_xor combine
  int node = t >> 2;
  int part = t & 3;
  int n = base_n + node;
  bool valid = n < NN;
  unsigned int ocv = valid ? oc[n] : 0u;
  int s0i = (int)(ocv >> 16);
  int c = (int)(ocv & 0xffffu);
  float2 adn = valid ? ad1[n] : make_float2(0.f, 0.f);
  float acc[10];
#pragma unroll
  for (int j = 0; j < 10; j++) acc[j] = 0.f;
  float den0 = 0.f, den1 = 0.f;
  for (int k = part; k < c; k += 4) {
    int s = (int)sorted[s0i + k];
    const float4* hs = (const float4*)(h1 + (size_t)s * 8);
    float4 ra = hs[0], rb = hs[1];
    float e0 = rb.z + adn.x; e0 = e0 > 0.f ? e0 : 0.2f * e0;
    float e1 = rb.w + adn.y; e1 = e1 > 0.f ? e1 : 0.2f * e1;
    float x0 = expf(e0), x1 = expf(e1);
    float2 h01 = uph(ra.x), h23 = uph(ra.y), h45 = uph(ra.z), h67 = uph(ra.w),
           h89 = uph(rb.x);
    acc[0] += x0 * h01.x;  acc[1] += x0 * h01.y;  acc[2] += x0 * h23.x;
    acc[3] += x0 * h23.y;  acc[4] += x0 * h45.x;
    acc[5] += x1 * h45.y;  acc[6] += x1 * h67.x;  acc[7] += x1 * h67.y;
    acc[8] += x1 * h89.x;  acc[9] += x1 * h89.y;
    den0 += x0; den1 += x1;
  }
#pragma unroll
  for (int j = 0; j < 10; j++) {
    acc[j] += __shfl_xor(acc[j], 1, 64);
    acc[j] += __shfl_xor(acc[j], 2, 64);
  }
  den0 += __shfl_xor(den0, 1, 64); den0 += __shfl_xor(den0, 2, 64);
  den1 += __shfl_xor(den1, 1, 64); den1 += __shfl_xor(den1, 2, 64);
  float v[10];
#pragma unroll
  for (int j = 0; j < 10; j++) v[j] = 0.f;
  if (part == 0 && valid) {
    // self-loop (src == dst == n)
    const float4* hs = (const float4*)(h1 + (size_t)n * 8);
    float4 ra = hs[0], rb = hs[1];
    float e0 = rb.z + adn.x; e0 = e0 > 0.f ? e0 : 0.2f * e0;
    float e1 = rb.w + adn.y; e1 = e1 > 0.f ? e1 : 0.2f * e1;
    float x0 = expf(e0), x1 = expf(e1);
    float2 h01 = uph(ra.x), h23 = uph(ra.y), h45 = uph(ra.z), h67 = uph(ra.w),
           h89 = uph(rb.x);
    acc[0] += x0 * h01.x;  acc[1] += x0 * h01.y;  acc[2] += x0 * h23.x;
    acc[3] += x0 * h23.y;  acc[4] += x0 * h45.x;
    acc[5] += x1 * h45.y;  acc[6] += x1 * h67.x;  acc[7] += x1 * h67.y;
    acc[8] += x1 * h89.x;  acc[9] += x1 * h89.y;
    den0 += x0; den1 += x1;
    float i0 = 1.f / (den0 + 1e-16f), i1 = 1.f / (den1 + 1e-16f);
#pragma unroll
    for (int j = 0; j < 5; j++) v[j] = acc[j] * i0 + biasS[j];
#pragma unroll
    for (int j = 5; j < 10; j++) v[j] = acc[j] * i1 + biasS[j];
    float4* gr = (float4*)(g1 + (size_t)n * 12);
    gr[0] = make_float4(v[0], v[1], v[2], v[3]);
    gr[1] = make_float4(v[4], v[5], v[6], v[7]);
    gr[2] = make_float4(v[8], v[9], 0.f, 0.f);
  }
  // BN partials: nonzero only at part==0 lanes (spacing 4) -> 4-stage reduce
  float s[20];
#pragma unroll
  for (int j = 0; j < 10; j++) { s[j] = v[j]; s[10 + j] = v[j] * v[j]; }
#pragma unroll
  for (int j = 0; j < 20; j++) {
    s[j] += __shfl_down(s[j], 4, 64);
    s[j] += __shfl_down(s[j], 8, 64);
    s[j] += __shfl_down(s[j], 16, 64);
    s[j] += __shfl_down(s[j], 32, 64);
  }
  if ((t & 63) == 0) {
#pragma unroll
    for (int j = 0; j < 20; j++) bn_lds[w * 20 + j] = s[j];
  }
  __syncthreads();
  if (t == 0) {
#pragma unroll
    for (int j = 0; j < 20; j++) {
      float acc20 = 0.f;
#pragma unroll
      for (int ww = 0; ww < 8; ww++) acc20 += bn_lds[ww * 20 + j];
      bn_part[j * BNP + b] = acc20;  // unique slot, no atomic
    }
  }
}

// ---- BN final reduce: one block per channel-stat, no contended atomics -----
__global__ __launch_bounds__(64) void k_bnred(const float* __restrict__ bn_part,
                                              float* __restrict__ bns) {
  int j = blockIdx.x;  // 0..19
  int lane = threadIdx.x;
  float s = 0.f;
  for (int b = lane; b < NBKT; b += 64) s += bn_part[j * BNP + b];
#pragma unroll
  for (int off = 32; off > 0; off >>= 1) s += __shfl_down(s, off, 64);
  if (lane == 0) bns[j] = s;
}

// -------- Layer 2 node: BN + ELU + h2 = hn@W2 -> fp16 row; as2 fp32 ---------
// h2 row (8 dwords): [o01,o23,o45,o67,o89 packed fp16, pad, ss, pad]
__global__ __launch_bounds__(256) void k_l2_node(
    const float* __restrict__ g1, const float* __restrict__ bns,
    const float* __restrict__ gamma1, const float* __restrict__ beta1,
    const float* __restrict__ W2, const float* __restrict__ a_src2,
    const float* __restrict__ a_dst2, float* __restrict__ h2,
    float* __restrict__ ad2) {
  __shared__ float scale[10], shift[10], W2s[100], a2s[10], a2d[10];
  if (threadIdx.x < 10) {
    int j = threadIdx.x;
    float mu = bns[j] * (1.f / NN);
    float var = bns[10 + j] * (1.f / NN) - mu * mu;
    float rs = rsqrtf(var + 1e-5f);
    scale[j] = rs * gamma1[j];
    shift[j] = beta1[j] - mu * rs * gamma1[j];
    a2s[j] = a_src2[j];
    a2d[j] = a_dst2[j];
  }
  for (int i = threadIdx.x; i < 100; i += blockDim.x) W2s[i] = W2[i];
  __syncthreads();
  int n = blockIdx.x * blockDim.x + threadIdx.x;
  if (n >= NN) return;
  const float4* gr = (const float4*)(g1 + (size_t)n * 12);
  float4 g0 = gr[0], g1v = gr[1], g2 = gr[2];
  float hv[10] = {g0.x, g0.y, g0.z, g0.w, g1v.x, g1v.y, g1v.z, g1v.w, g2.x, g2.y};
#pragma unroll
  for (int j = 0; j < 10; j++) {
    float t = hv[j] * scale[j] + shift[j];
    hv[j] = t > 0.f ? t : expm1f(t);  // ELU
  }
  float o[10];
#pragma unroll
  for (int k = 0; k < 10; k++) o[k] = 0.f;
#pragma unroll
  for (int c = 0; c < 10; c++) {
#pragma unroll
    for (int k = 0; k < 10; k++) o[k] += hv[c] * W2s[c * 10 + k];
  }
  float ss = 0.f, sd = 0.f;
#pragma unroll
  for (int k = 0; k < 10; k++) { ss += o[k] * a2s[k]; sd += o[k] * a2d[k]; }
  float4* hr = (float4*)(h2 + (size_t)n * 8);
  hr[0] = make_float4(pkh(o[0], o[1]), pkh(o[2], o[3]), pkh(o[4], o[5]),
                      pkh(o[6], o[7]));
  hr[1] = make_float4(pkh(o[8], o[9]), 0.f, ss, 0.f);
  ad2[n] = sd;
}

// ---- L2 agg: LDS-stage pre-sorted bucket, 1 head, writes final out ---------
__global__ __launch_bounds__(512, 8) void k_l2_aggs(
    const int* __restrict__ bcnt,
    const unsigned int* __restrict__ sorted_g, const unsigned int* __restrict__ oc,
    const float* __restrict__ h2, const float* __restrict__ ad2,
    const float* __restrict__ b2, float* __restrict__ out) {
  __shared__ __align__(16) unsigned int sorted[BCAP];
  __shared__ float biasS[10];
  int t = threadIdx.x;
  int b = blockIdx.x;
  int base_n = b << BSH;
  if (t < 10) biasS[t] = b2[t];
  {
    int cb = bcnt[b];
    cb = cb > BCAP ? BCAP : cb;
    int n4 = (cb + 3) >> 2;
    const uint4* pp4 = (const uint4*)(sorted_g + (size_t)b * BCAP);
    uint4* s4 = (uint4*)sorted;
    for (int k = t; k < n4; k += 512) s4[k] = pp4[k];
  }
  __syncthreads();
  int node = t >> 2;
  int part = t & 3;
  int n = base_n + node;
  bool valid = n < NN;
  unsigned int ocv = valid ? oc[n] : 0u;
  int s0i = (int)(ocv >> 16);
  int c = (int)(ocv & 0xffffu);
  float adn = valid ? ad2[n] : 0.f;
  float acc[10];
#pragma unroll
  for (int j = 0; j < 10; j++) acc[j] = 0.f;
  float den = 0.f;
  for (int k = part; k < c; k += 4) {
    int s = (int)sorted[s0i + k];
    const float4* hs = (const float4*)(h2 + (size_t)s * 8);
    float4 ra = hs[0], rb = hs[1];
    float ee = rb.z + adn; ee = ee > 0.f ? ee : 0.2f * ee;
    float xv = expf(ee);
    float2 h01 = uph(ra.x), h23 = uph(ra.y), h45 = uph(ra.z), h67 = uph(ra.w),
           h89 = uph(rb.x);
    acc[0] += xv * h01.x;  acc[1] += xv * h01.y;  acc[2] += xv * h23.x;
    acc[3] += xv * h23.y;  acc[4] += xv * h45.x;  acc[5] += xv * h45.y;
    acc[6] += xv * h67.x;  acc[7] += xv * h67.y;  acc[8] += xv * h89.x;
    acc[9] += xv * h89.y;
    den += xv;
  }
#pragma unroll
  for (int j = 0; j < 10; j++) {
    acc[j] += __shfl_xor(acc[j], 1, 64);
    acc[j] += __shfl_xor(acc[j], 2, 64);
  }
  den += __shfl_xor(den, 1, 64); den += __shfl_xor(den, 2, 64);
  if (part == 0 && valid) {
    const float4* hs = (const float4*)(h2 + (size_t)n * 8);  // self-loop
    float4 ra = hs[0], rb = hs[1];
    float ee = rb.z + adn; ee = ee > 0.f ? ee : 0.2f * ee;
    float xv = expf(ee);
    float2 h01 = uph(ra.x), h23 = uph(ra.y), h45 = uph(ra.z), h67 = uph(ra.w),
           h89 = uph(rb.x);
    acc[0] += xv * h01.x;  acc[1] += xv * h01.y;  acc[2] += xv * h23.x;
    acc[3] += xv * h23.y;  acc[4] += xv * h45.x;  acc[5] += xv * h45.y;
    acc[6] += xv * h67.x;  acc[7] += xv * h67.y;  acc[8] += xv * h89.x;
    acc[9] += xv * h89.y;
    den += xv;
    float inv = 1.f / (den + 1e-16f);
    float2* orow = (float2*)(out + (size_t)n * 10);
    orow[0] = make_float2(acc[0] * inv + biasS[0], acc[1] * inv + biasS[1]);
    orow[1] = make_float2(acc[2] * inv + biasS[2], acc[3] * inv + biasS[3]);
    orow[2] = make_float2(acc[4] * inv + biasS[4], acc[5] * inv + biasS[5]);
    orow[3] = make_float2(acc[6] * inv + biasS[6], acc[7] * inv + biasS[7]);
    orow[4] = make_float2(acc[8] * inv + biasS[8], acc[9] * inv + biasS[9]);
  }
}

extern "C" void kernel_launch(void* const* d_in, const int* in_sizes, int n_in,
                              void* d_out, int out_size, void* d_ws, size_t ws_size,
                              hipStream_t stream) {
  const float* x      = (const float*)d_in[0];
  const float* W1     = (const float*)d_in[1];
  const float* a_src1 = (const float*)d_in[2];
  const float* a_dst1 = (const float*)d_in[3];
  const float* b1     = (const float*)d_in[4];
  const float* gamma1 = (const float*)d_in[5];
  const float* beta1  = (const float*)d_in[6];
  const float* W2     = (const float*)d_in[7];
  const float* a_src2 = (const float*)d_in[8];
  const float* a_dst2 = (const float*)d_in[9];
  const float* b2     = (const float*)d_in[10];
  const int*   ei     = (const int*)d_in[11];
  float* out = (float*)d_out;

  // Workspace layout (4B units). All regions fully written before read.
  int* bcnt = (int*)d_ws;                               // NBKT (k_scanb writes)
  unsigned int* pairs = (unsigned int*)d_ws + 1024;     // NBKT*BCAP
  float* h1 = (float*)(pairs + (size_t)NBKT * BCAP);    // NN*8 (fp16 rows)
  float* ad1 = h1 + (size_t)NN * 8;                     // NN*2
  float* g1 = ad1 + (size_t)NN * 2;                     // NN*12
  float* h2 = g1 + (size_t)NN * 12;                     // NN*8 (fp16 rows)
  float* ad2 = h2 + (size_t)NN * 8;                     // NN
  float* bn_part = ad2 + NN;                            // 20*BNP
  float* bns = bn_part + 20 * BNP;                      // 20
  int* cntmat = (int*)(bns + 20 + 12);                  // NBKT*NBP
  int* basemat = cntmat + (size_t)NBKT * NBP;           // NBKT*NBP
  unsigned int* oc = (unsigned int*)(basemat + (size_t)NBKT * NBP);  // NN

  const int B = 256;
  const int gN = (NN + B - 1) / B;               // 391
  const int gBin = (NE + BIN_CH - 1) / BIN_CH;   // 782

  k_count<<<gBin, 512, 0, stream>>>(ei, cntmat);
  k_scanb<<<NBKT, 64, 0, stream>>>(cntmat, basemat, bcnt);
  k_scatter2<<<gBin, 1024, 0, stream>>>(ei, cntmat, basemat, pairs);
  k_sortb<<<NBKT, 1024, 0, stream>>>(bcnt, pairs, oc);
  k_l1_node<<<gN, B, 0, stream>>>(x, W1, a_src1, a_dst1, h1, (float2*)ad1);
  k_l1_aggs<<<NBKT, 512, 0, stream>>>(bcnt, pairs, oc, h1, (const float2*)ad1,
                                      b1, g1, bn_part);
  k_bnred<<<20, 64, 0, stream>>>(bn_part, bns);
  k_l2_node<<<gN, B, 0, stream>>>(g1, bns, gamma1, beta1, W2, a_src2, a_dst2,
                                  h2, ad2);
  k_l2_aggs<<<NBKT, 512, 0, stream>>>(bcnt, pairs, oc, h2, ad2, b2, out);
}